// Round 13
// baseline (15002.870 us; speedup 1.0000x reference)
//
#include <hip/hip_runtime.h>
#include <hip/hip_bf16.h>
#include <stdint.h>

typedef unsigned short u16;
typedef uint32_t u32;
typedef unsigned long long u64;
typedef float f32x4 __attribute__((ext_vector_type(4)));
typedef __bf16 bf16x8 __attribute__((ext_vector_type(8)));

__device__ inline u16 f2bf(float f) {
  __bf16 h = (__bf16)f;                 // RTNE
  return __builtin_bit_cast(u16, h);
}
__device__ inline f32x4 mfma16(bf16x8 a, bf16x8 b, f32x4 c) {
  return __builtin_amdgcn_mfma_f32_16x16x32_bf16(a, b, c, 0, 0, 0);
}
// split 8 contiguous fp32 into bf16 hi + lo fragments (cached loads)
__device__ inline void cvt8(const float* p, bf16x8& h, bf16x8& l) {
  f32x4 u = *(const f32x4*)p;
  f32x4 v = *(const f32x4*)(p + 4);
#pragma unroll
  for (int i = 0; i < 4; ++i) {
    float a = u[i]; __bf16 ah = (__bf16)a; h[i] = ah; l[i] = (__bf16)(a - (float)ah);
    float b = v[i]; __bf16 bh = (__bf16)b; h[i + 4] = bh; l[i + 4] = (__bf16)(b - (float)bh);
  }
}
// gather 8 k-strided fp32 (stride 1024 floats) into bf16 hi + lo fragments
__device__ inline void gather8(const float* p, bf16x8& h, bf16x8& l) {
#pragma unroll
  for (int e = 0; e < 8; ++e) {
    float f = p[(size_t)e * 1024];
    __bf16 x = (__bf16)f;
    h[e] = x; l[e] = (__bf16)(f - (float)x);
  }
}

// ---- coherence-point (bypass) accessors ----
__device__ inline u64 ld64(const u64* p) {
  return __hip_atomic_load(p, __ATOMIC_RELAXED, __HIP_MEMORY_SCOPE_AGENT);
}
__device__ inline u32 ld32(const u32* p) {
  return __hip_atomic_load(p, __ATOMIC_RELAXED, __HIP_MEMORY_SCOPE_AGENT);
}
__device__ inline void st32(u32* p, u32 v) {
  __hip_atomic_store(p, v, __ATOMIC_RELAXED, __HIP_MEMORY_SCOPE_AGENT);
}
__device__ inline void st64(u64* p, u64 v) {
  __hip_atomic_store(p, v, __ATOMIC_RELAXED, __HIP_MEMORY_SCOPE_AGENT);
}

// Epoch-tagged state plane: u64 word = {epoch32 | bf16pair32}, layout
// word[(j>>1)*32 + b]. 128KB per plane. ONE coalesced 32-word load per
// phase, issued inside the barrier window; tags verified post-barrier.
struct W4 { u32 w[4]; };
__device__ inline void load32(const u64* p, u64 q[32]) {
#pragma unroll
  for (int ks = 0; ks < 4; ++ks) {
#pragma unroll
    for (int p4 = 0; p4 < 4; ++p4) {
      q[ks * 8 + p4]     = ld64(p + ks * 512 + p4 * 32);
      q[ks * 8 + 4 + p4] = ld64(p + ks * 512 + p4 * 32 + 16);
    }
  }
}
__device__ inline bool check32(const u64 q[32], u32 tag) {
  bool ok = true;
#pragma unroll
  for (int i = 0; i < 32; ++i) ok &= ((u32)(q[i] >> 32) == tag);
  return ok;
}
// post-barrier fixup: bounded, FULL-WIDTH coalesced reloads (no divergence)
__device__ inline void fix32(const u64* p, u32 tag, u64 q[32]) {
  bool ok = check32(q, tag);
  int it = 0;
  while (__ballot(!ok) != 0ull) {
    load32(p, q);                       // all lanes together: coalesced
    ok = check32(q, tag);
    if (++it > 64) break;               // garbage > hang
  }
}
__device__ inline bf16x8 lo4(const u64* q) {
  W4 a = {{(u32)q[0], (u32)q[1], (u32)q[2], (u32)q[3]}};
  return __builtin_bit_cast(bf16x8, a);
}

struct RecArgs {
  const float* x;
  const float *W_ix, *W_ih, *W_ic, *W_fx, *W_fh, *W_fc, *W_cx, *W_ch;
  const float *W_ox, *W_oh, *W_oc;
  const float *b_i, *b_f, *b_c, *b_o;
  u64 *hE, *cE;          // epoch-tagged state planes, 128KB each
  u32* flags;            // 256 per-block epoch flags
  u32* done;             // root broadcast epoch (own line)
  float* out;
};

// Tree barrier split into arrive/wait so tagged state loads can be issued
// inside the propagation window (speculation verified by tags afterwards).
__device__ inline void arriveT(u32* flags, unsigned ep, int wg) {
  __syncthreads();                      // drain state stores to IF$ first
  if (threadIdx.x == 0) st32(flags + wg, ep);
}
__device__ inline void waitT(u32* flags, u32* done, unsigned ep, int wg) {
  const int tid = threadIdx.x;
  if (wg == 0) {
    const int wv = tid >> 6, ln = tid & 63;
    if (wv < 4) {
      int it = 0;
      for (;;) {
        u32 v = ld32(flags + wv * 64 + ln);
        if (__ballot(v >= ep) == ~0ull) break;
        if (++it > 400000) break;
        __builtin_amdgcn_s_sleep(1);
      }
    }
    __syncthreads();                    // all quarter-groups confirmed
    if (tid == 0) st32(done, ep);
  }
  if (tid == 0) {
    int it = 0;
    while (ld32(done) < ep && it < 400000) {
      __builtin_amdgcn_s_sleep(1);
      ++it;
    }
  }
  __syncthreads();
}

// Persistent LSTM: 256 blocks x 512 threads (8 waves). Block owns 4 H-cols
// of each gate; wave w owns K-slice [w*128,(w+1)*128). Weights register-
// resident (hi/lo bf16). Tree barrier + in-window tagged state speculation.
// Arithmetic order bit-identical to round-9/11 (absmax 0.01708984).
__global__ __launch_bounds__(512, 1) void lstm_rec(RecArgs a) {
  __shared__ float scr[8 * 2 * 16 * 17];     // [wave][mt][row][col], padded

  const int tid = threadIdx.x;
  const int wg = blockIdx.x;
  const int j0 = wg * 4;
  const int lane = tid & 63;
  const int wave = tid >> 6;
  const int mrow = lane & 15;               // A-row (batch) lane index
  const int kgroup = lane >> 4;             // k sub-block 0..3
  const int kq = kgroup * 8;
  const int kw = wave * 128;                // per-wave K slice
  const int col = lane & 15;                // B/D column lane index
  const int rq = (lane >> 4) * 4;           // D row quad base
  const int pbase = (wave * 16 + kgroup) * 128 + mrow;

  // ---- one-time: B-fragments (weights) -> registers, hi/lo split ----
  const int fjj = col >> 2, fg = col & 3;   // col = jj*4 + g
  const int fj = j0 + fjj;
  const float* Wx = (fg == 0) ? a.W_ix : (fg == 1) ? a.W_fx : (fg == 2) ? a.W_cx : a.W_ox;
  const float* Wh = (fg == 0) ? a.W_ih : (fg == 1) ? a.W_fh : (fg == 2) ? a.W_ch : a.W_oh;
  const float* Wc = (fg == 0) ? a.W_ic : (fg == 1) ? a.W_fc : (fg == 3) ? a.W_oc : a.W_ic;

  bf16x8 bxh[4], bxl[4], bhh[4], bhl[4], bch[4], bcl[4];
#pragma unroll
  for (int ks = 0; ks < 4; ++ks) {
    const size_t k8 = (size_t)(kw + ks * 32 + kq);
    gather8(Wx + k8 * 1024 + fj, bxh[ks], bxl[ks]);
    gather8(Wh + k8 * 1024 + fj, bhh[ks], bhl[ks]);
    if (fg != 2) {
      gather8(Wc + k8 * 1024 + fj, bch[ks], bcl[ks]);
    } else {
      bf16x8 z = {};
      bch[ks] = z; bcl[ks] = z;
    }
  }

  // elementwise thread constants (threads 0..127: b = tid>>2, jj = tid&3)
  const int eb = tid >> 2, ejj = tid & 3, ej = j0 + (tid & 3);
  const int widx = (ej >> 1) * 32 + eb;     // tagged-word index of own pair
  // ---- init own state words: {tag=0 | 0.0bf16 pair} ----
  if (tid < 128 && (tid & 1) == 0) {
    st64(a.hE + widx, 0ull);
    st64(a.cE + widx, 0ull);
  }
  float bi = 0.f, bfv = 0.f, bcv = 0.f, bo = 0.f;
  if (tid < 128) {
    bi = a.b_i[ej]; bfv = a.b_f[eb * 1024 + ej]; bcv = a.b_c[ej]; bo = a.b_o[ej];
  }

  unsigned ep = 0;
  u64 qh[32], qc[32];
  arriveT(a.flags, ++ep, wg);
  load32(a.hE + pbase, qh);                 // speculative h(tag 0)
  waitT(a.flags, a.done, ep, wg);
  fix32(a.hE + pbase, 0u, qh);

  float c_reg = 0.f, o_pre = 0.f;
  bf16x8 cf0[4] = {}, cf1[4] = {};          // carried c_{t-1} fragments

  for (int t = 0; t < 512; ++t) {
    // ======== phase 1: pre-gates = x@Wx + h@Wh + c_{t-1}@Wc ========
    // peephole chain: separate accumulator (bit-order-independent vs acc)
    f32x4 pc0 = {}, pc1 = {};
#pragma unroll
    for (int ks = 0; ks < 4; ++ks) {
      pc0 = mfma16(cf0[ks], bch[ks], pc0);
      pc0 = mfma16(cf0[ks], bcl[ks], pc0);
      pc1 = mfma16(cf1[ks], bch[ks], pc1);
      pc1 = mfma16(cf1[ks], bcl[ks], pc1);
    }
    // MFMA chain in EXACT round-9 order (per-ks x/h interleave)
    f32x4 acc0 = {}, acc1 = {};
#pragma unroll
    for (int ks = 0; ks < 4; ++ks) {
      const int ka = kw + ks * 32 + kq;
      bf16x8 ah0 = lo4(qh + ks * 8);
      bf16x8 ah1 = lo4(qh + ks * 8 + 4);
      bf16x8 xh0, xl0, xh1, xl1;
      const float* xp = a.x + ((size_t)(t * 32 + mrow) << 10) + ka;
      cvt8(xp, xh0, xl0);
      cvt8(xp + (16 << 10), xh1, xl1);
      acc0 = mfma16(xh0, bxh[ks], acc0);
      acc0 = mfma16(xl0, bxh[ks], acc0);
      acc0 = mfma16(xh0, bxl[ks], acc0);
      acc0 = mfma16(ah0, bhh[ks], acc0);
      acc0 = mfma16(ah0, bhl[ks], acc0);
      acc1 = mfma16(xh1, bxh[ks], acc1);
      acc1 = mfma16(xl1, bxh[ks], acc1);
      acc1 = mfma16(xh1, bxl[ks], acc1);
      acc1 = mfma16(ah1, bhh[ks], acc1);
      acc1 = mfma16(ah1, bhl[ks], acc1);
    }
    {
      const bool take_pc = (col & 3) != 3;   // o-gate peephole deferred
#pragma unroll
      for (int v = 0; v < 4; ++v) {
        scr[((wave * 2 + 0) * 16 + rq + v) * 17 + col] = acc0[v] + (take_pc ? pc0[v] : 0.f);
        scr[((wave * 2 + 1) * 16 + rq + v) * 17 + col] = acc1[v] + (take_pc ? pc1[v] : 0.f);
      }
    }
    __syncthreads();
    if (tid < 128) {
      float pre[4];
#pragma unroll
      for (int g = 0; g < 4; ++g) {
        float s = 0.f;
#pragma unroll
        for (int w = 0; w < 8; ++w)
          s += scr[((w * 2 + (eb >> 4)) * 16 + (eb & 15)) * 17 + ejj * 4 + g];
        pre[g] = s;
      }
      float iv = 1.f / (1.f + expf(-(pre[0] + bi)));
      float fv = 1.f / (1.f + expf(-(pre[1] + bfv)));
      float cv = tanhf(pre[2] + bcv);
      c_reg = fv * c_reg + iv * cv;           // fp32 carry, owner thread
      u32 cb = (u32)f2bf(c_reg);
      u32 cpart = __shfl_xor(cb, 1);
      if ((tid & 1) == 0)
        st64(a.cE + widx, ((u64)(u32)(t + 1) << 32) | (u64)(cb | (cpart << 16)));
      o_pre = pre[3] + bo;
    }
    arriveT(a.flags, ++ep, wg);               // c_t barrier: arrive
    load32(a.cE + pbase, qc);                 // speculative c_t (in window)
    waitT(a.flags, a.done, ep, wg);
    fix32(a.cE + pbase, (u32)(t + 1), qc);

    // ======== phase 2: o-gate peephole = c_t @ W_oc ========
    f32x4 a20 = {}, a21 = {};
#pragma unroll
    for (int ks = 0; ks < 4; ++ks) {
      cf0[ks] = lo4(qc + ks * 8);             // save as carry for phase1(t+1)
      cf1[ks] = lo4(qc + ks * 8 + 4);
      a20 = mfma16(cf0[ks], bch[ks], a20);
      a20 = mfma16(cf0[ks], bcl[ks], a20);
      a21 = mfma16(cf1[ks], bch[ks], a21);
      a21 = mfma16(cf1[ks], bcl[ks], a21);
    }
#pragma unroll
    for (int v = 0; v < 4; ++v) {
      scr[((wave * 2 + 0) * 16 + rq + v) * 17 + col] = a20[v];
      scr[((wave * 2 + 1) * 16 + rq + v) * 17 + col] = a21[v];
    }
    __syncthreads();
    if (tid < 128) {
      float s = o_pre;
#pragma unroll
      for (int w = 0; w < 8; ++w)
        s += scr[((w * 2 + (eb >> 4)) * 16 + (eb & 15)) * 17 + ejj * 4 + 3];
      float ov = 1.f / (1.f + expf(-s));
      float hv = ov * tanhf(c_reg);
      u32 hb = (u32)f2bf(hv);
      u32 hpart = __shfl_xor(hb, 1);
      if ((tid & 1) == 0)
        st64(a.hE + widx, ((u64)(u32)(t + 1) << 32) | (u64)(hb | (hpart << 16)));
      if (t == 511) a.out[eb * 1024 + ej] = hv;
    }
    arriveT(a.flags, ++ep, wg);               // h_t barrier: arrive
    if (t < 511) load32(a.hE + pbase, qh);    // speculative h_t (in window)
    waitT(a.flags, a.done, ep, wg);
    if (t < 511) fix32(a.hE + pbase, (u32)(t + 1), qh);
  }
}

extern "C" void kernel_launch(void* const* d_in, const int* in_sizes, int n_in,
                              void* d_out, int out_size, void* d_ws, size_t ws_size,
                              hipStream_t stream) {
  (void)in_sizes; (void)n_in; (void)out_size;
  RecArgs ra;
  ra.x    = (const float*)d_in[0];
  ra.W_ix = (const float*)d_in[1];
  ra.W_ih = (const float*)d_in[2];
  ra.W_ic = (const float*)d_in[3];
  ra.W_fx = (const float*)d_in[4];
  ra.W_fh = (const float*)d_in[5];
  ra.W_fc = (const float*)d_in[6];
  ra.W_cx = (const float*)d_in[7];
  ra.W_ch = (const float*)d_in[8];
  ra.W_ox = (const float*)d_in[9];
  ra.W_oh = (const float*)d_in[10];
  ra.W_oc = (const float*)d_in[11];
  ra.b_i  = (const float*)d_in[12];
  ra.b_f  = (const float*)d_in[13];
  ra.b_c  = (const float*)d_in[14];
  ra.b_o  = (const float*)d_in[15];

  char* ws = (char*)d_ws;
  size_t off = 0;
  auto alloc = [&](size_t bytes) {
    char* p = ws + off;
    off = (off + bytes + 255) & ~(size_t)255;
    return p;
  };
  ra.hE    = (u64*)alloc(16384 * 8);   // epoch-tagged h plane (128KB)
  ra.cE    = (u64*)alloc(16384 * 8);   // epoch-tagged c plane (128KB)
  ra.flags = (u32*)alloc(1024);        // 256 per-block epoch flags
  ra.done  = (u32*)alloc(256);         // root broadcast epoch (own line)
  ra.out   = (float*)d_out;
  if (off > ws_size) return;           // visible failure if ws too small

  (void)hipMemsetAsync(ra.flags, 0, 1024, stream);
  (void)hipMemsetAsync(ra.done, 0, 256, stream);

  void* args[] = {&ra};
  hipError_t e = hipLaunchCooperativeKernel((void*)lstm_rec, dim3(256), dim3(512),
                                            args, 0, stream);
  if (e != hipSuccess) {
    // co-residency still holds: 1 block/CU x 256 blocks on 256 CUs
    lstm_rec<<<dim3(256), dim3(512), 0, stream>>>(ra);
  }
}

// Round 14
// 5457.977 us; speedup vs baseline: 2.7488x; 2.7488x over previous
//
#include <hip/hip_runtime.h>
#include <hip/hip_bf16.h>
#include <stdint.h>

typedef unsigned short u16;
typedef uint32_t u32;
typedef unsigned long long u64;
typedef float f32x4 __attribute__((ext_vector_type(4)));
typedef __bf16 bf16x8 __attribute__((ext_vector_type(8)));

__device__ inline u16 f2bf(float f) {
  __bf16 h = (__bf16)f;                 // RTNE
  return __builtin_bit_cast(u16, h);
}
__device__ inline f32x4 mfma16(bf16x8 a, bf16x8 b, f32x4 c) {
  return __builtin_amdgcn_mfma_f32_16x16x32_bf16(a, b, c, 0, 0, 0);
}
// split 8 contiguous fp32 into bf16 hi + lo fragments (cached loads)
__device__ inline void cvt8(const float* p, bf16x8& h, bf16x8& l) {
  f32x4 u = *(const f32x4*)p;
  f32x4 v = *(const f32x4*)(p + 4);
#pragma unroll
  for (int i = 0; i < 4; ++i) {
    float a = u[i]; __bf16 ah = (__bf16)a; h[i] = ah; l[i] = (__bf16)(a - (float)ah);
    float b = v[i]; __bf16 bh = (__bf16)b; h[i + 4] = bh; l[i + 4] = (__bf16)(b - (float)bh);
  }
}
// gather 8 k-strided fp32 (stride 1024 floats) into bf16 hi + lo fragments
__device__ inline void gather8(const float* p, bf16x8& h, bf16x8& l) {
#pragma unroll
  for (int e = 0; e < 8; ++e) {
    float f = p[(size_t)e * 1024];
    __bf16 x = (__bf16)f;
    h[e] = x; l[e] = (__bf16)(f - (float)x);
  }
}

// ---- coherence-point (bypass) accessors ----
__device__ inline u64 ld64(const u64* p) {
  return __hip_atomic_load(p, __ATOMIC_RELAXED, __HIP_MEMORY_SCOPE_AGENT);
}
__device__ inline u32 ld32(const u32* p) {
  return __hip_atomic_load(p, __ATOMIC_RELAXED, __HIP_MEMORY_SCOPE_AGENT);
}
__device__ inline void st32(u32* p, u32 v) {
  __hip_atomic_store(p, v, __ATOMIC_RELAXED, __HIP_MEMORY_SCOPE_AGENT);
}

// bf16 state plane [32 b][1024 j], 64KB, k-contiguous layout (u16 units):
//   idx16(b,j) = (j>>3)<<8 | ((j>>2)&1)<<7 | (b&31)<<2 | (j&3)
// A wave fragment (8 k-elems, one row) = 2 coalesced ld64.  [R8-exact]
struct B16Pair { u64 a, b; };
__device__ inline bf16x8 ldfrag(const u64* base, int j8, int row) {
  B16Pair p;
  p.a = ld64(base + (j8 << 6) + row);
  p.b = ld64(base + (j8 << 6) + 32 + row);
  return __builtin_bit_cast(bf16x8, p);
}

struct RecArgs {
  const float* x;
  const float *W_ix, *W_ih, *W_ic, *W_fx, *W_fh, *W_fc, *W_cx, *W_ch;
  const float *W_ox, *W_oh, *W_oc;
  const float *b_i, *b_f, *b_c, *b_o;
  u32 *hB, *cB;          // bf16 state planes, 64KB each
  u32* flags;            // 256 per-block epoch flags
  u32* done;             // root broadcast epoch (own line)
  float* out;
};

// R8 tree barrier, split into arrive/wait so independent register work can
// fill the propagation window. Protocol identical to round 8 (5.12ms best).
__device__ inline void arriveT(u32* flags, unsigned ep, int wg) {
  __syncthreads();                      // drain state stores to IF$ first
  if (threadIdx.x == 0) st32(flags + wg, ep);
}
__device__ inline void waitT(u32* flags, u32* done, unsigned ep, int wg) {
  const int tid = threadIdx.x;
  if (wg == 0) {
    const int wv = tid >> 6, ln = tid & 63;
    if (wv < 4) {
      int it = 0;
      for (;;) {
        u32 v = ld32(flags + wv * 64 + ln);
        if (__ballot(v >= ep) == ~0ull) break;
        if (++it > 400000) break;
        __builtin_amdgcn_s_sleep(1);
      }
    }
    __syncthreads();                    // all quarter-groups confirmed
    if (tid == 0) st32(done, ep);
  }
  if (tid == 0) {
    int it = 0;
    while (ld32(done) < ep && it < 400000) {
      __builtin_amdgcn_s_sleep(1);
      ++it;
    }
  }
  __syncthreads();
}

// Persistent LSTM: 256 blocks x 512 threads (8 waves). Block owns 4 H-cols
// of each gate; wave w owns K-slice. Weights register-resident (hi/lo bf16).
// R8 structure + barrier-window filling: x(t+1) cvt in the c-window, the
// (t+1) peephole MFMA chain in the h-window. Numerics bit-exact vs R8.
__global__ __launch_bounds__(512, 1) void lstm_rec(RecArgs a) {
  __shared__ float scr[8 * 2 * 16 * 17];     // [wave][mt][row][col], padded

  const int tid = threadIdx.x;
  const int wg = blockIdx.x;
  const int j0 = wg * 4;
  const int lane = tid & 63;
  const int wave = tid >> 6;
  const int mrow = lane & 15;               // A-row (batch) lane index
  const int kgroup = lane >> 4;             // k sub-block 0..3
  const int kq = kgroup * 8;
  const int kw = wave * 128;                // per-wave K slice
  const int col = lane & 15;                // B/D column lane index
  const int rq = (lane >> 4) * 4;           // D row quad base

  const u64* H64 = (const u64*)a.hB;
  const u64* C64 = (const u64*)a.cB;

  // ---- one-time: B-fragments (weights) -> registers, hi/lo split ----
  const int fjj = col >> 2, fg = col & 3;   // col = jj*4 + g
  const int fj = j0 + fjj;
  const float* Wx = (fg == 0) ? a.W_ix : (fg == 1) ? a.W_fx : (fg == 2) ? a.W_cx : a.W_ox;
  const float* Wh = (fg == 0) ? a.W_ih : (fg == 1) ? a.W_fh : (fg == 2) ? a.W_ch : a.W_oh;
  const float* Wc = (fg == 0) ? a.W_ic : (fg == 1) ? a.W_fc : (fg == 3) ? a.W_oc : a.W_ic;

  bf16x8 bxh[4], bxl[4], bhh[4], bhl[4], bch[4], bcl[4];
#pragma unroll
  for (int ks = 0; ks < 4; ++ks) {
    const size_t k8 = (size_t)(kw + ks * 32 + kq);
    gather8(Wx + k8 * 1024 + fj, bxh[ks], bxl[ks]);
    gather8(Wh + k8 * 1024 + fj, bhh[ks], bhl[ks]);
    if (fg != 2) {
      gather8(Wc + k8 * 1024 + fj, bch[ks], bcl[ks]);
    } else {
      bf16x8 z = {};
      bch[ks] = z; bcl[ks] = z;
    }
  }

  // elementwise thread constants (threads 0..127: b = tid>>2, jj = tid&3)
  const int eb = tid >> 2, ejj = tid & 3, ej = j0 + (tid & 3);
  const u32 swidx = ((u32)(ej >> 3) << 7) | ((u32)((ej >> 2) & 1) << 6)
                  | ((u32)eb << 1) | ((u32)(ej >> 1) & 1);
  // ---- zero own slice of state (bypass stores, even threads store pairs) --
  if (tid < 128 && (tid & 1) == 0) {
    st32(a.hB + swidx, 0u);
    st32(a.cB + swidx, 0u);
  }
  float bi = 0.f, bfv = 0.f, bcv = 0.f, bo = 0.f;
  if (tid < 128) {
    bi = a.b_i[ej]; bfv = a.b_f[eb * 1024 + ej]; bcv = a.b_c[ej]; bo = a.b_o[ej];
  }

  unsigned ep = 0;
  arriveT(a.flags, ++ep, wg);
  // init-barrier window: prefetch x(0) fragments
  bf16x8 xph0[4], xpl0[4], xph1[4], xpl1[4];
#pragma unroll
  for (int ks = 0; ks < 4; ++ks) {
    const float* xp = a.x + ((size_t)mrow << 10) + kw + ks * 32 + kq;
    cvt8(xp, xph0[ks], xpl0[ks]);
    cvt8(xp + (16 << 10), xph1[ks], xpl1[ks]);
  }
  waitT(a.flags, a.done, ep, wg);

  float c_reg = 0.f, o_pre = 0.f;
  bf16x8 cf0[4] = {}, cf1[4] = {};          // carried c_{t-1} fragments
  // prologue peephole chain for t=0 (zero cf -> exact 0, as in R8's t=0)
  f32x4 pc0 = {}, pc1 = {};
#pragma unroll
  for (int ks = 0; ks < 4; ++ks) {
    pc0 = mfma16(cf0[ks], bch[ks], pc0);
    pc0 = mfma16(cf0[ks], bcl[ks], pc0);
    pc1 = mfma16(cf1[ks], bch[ks], pc1);
    pc1 = mfma16(cf1[ks], bcl[ks], pc1);
  }

  for (int t = 0; t < 512; ++t) {
    // ======== phase 1: pre-gates = x@Wx + h@Wh (+ pc from window) ========
    f32x4 acc0 = {}, acc1 = {};
#pragma unroll
    for (int ks = 0; ks < 4; ++ks) {
      const int j8 = wave * 16 + ks * 4 + kgroup;
      bf16x8 ah0 = ldfrag(H64, j8, mrow);
      bf16x8 ah1 = ldfrag(H64, j8, mrow + 16);
      acc0 = mfma16(xph0[ks], bxh[ks], acc0);
      acc0 = mfma16(xpl0[ks], bxh[ks], acc0);
      acc0 = mfma16(xph0[ks], bxl[ks], acc0);
      acc0 = mfma16(ah0, bhh[ks], acc0);
      acc0 = mfma16(ah0, bhl[ks], acc0);
      acc1 = mfma16(xph1[ks], bxh[ks], acc1);
      acc1 = mfma16(xpl1[ks], bxh[ks], acc1);
      acc1 = mfma16(xph1[ks], bxl[ks], acc1);
      acc1 = mfma16(ah1, bhh[ks], acc1);
      acc1 = mfma16(ah1, bhl[ks], acc1);
    }
    {
      const bool take_pc = (col & 3) != 3;   // o-gate peephole deferred
#pragma unroll
      for (int v = 0; v < 4; ++v) {
        scr[((wave * 2 + 0) * 16 + rq + v) * 17 + col] = acc0[v] + (take_pc ? pc0[v] : 0.f);
        scr[((wave * 2 + 1) * 16 + rq + v) * 17 + col] = acc1[v] + (take_pc ? pc1[v] : 0.f);
      }
    }
    __syncthreads();
    if (tid < 128) {
      float pre[4];
#pragma unroll
      for (int g = 0; g < 4; ++g) {
        float s = 0.f;
#pragma unroll
        for (int w = 0; w < 8; ++w)
          s += scr[((w * 2 + (eb >> 4)) * 16 + (eb & 15)) * 17 + ejj * 4 + g];
        pre[g] = s;
      }
      float iv = 1.f / (1.f + expf(-(pre[0] + bi)));
      float fv = 1.f / (1.f + expf(-(pre[1] + bfv)));
      float cv = tanhf(pre[2] + bcv);
      c_reg = fv * c_reg + iv * cv;           // fp32 carry, owner thread
      u32 cb = (u32)f2bf(c_reg);
      u32 cpart = __shfl_xor(cb, 1);
      if ((tid & 1) == 0) st32(a.cB + swidx, cb | (cpart << 16));
      o_pre = pre[3] + bo;
    }
    arriveT(a.flags, ++ep, wg);               // c_t barrier: arrive
    // ---- c-window: prefetch + convert x(t+1) (L2-cached, independent) ----
    {
      const int tn = (t < 511) ? t + 1 : 511;
#pragma unroll
      for (int ks = 0; ks < 4; ++ks) {
        const float* xp = a.x + ((size_t)(tn * 32 + mrow) << 10) + kw + ks * 32 + kq;
        cvt8(xp, xph0[ks], xpl0[ks]);
        cvt8(xp + (16 << 10), xph1[ks], xpl1[ks]);
      }
    }
    waitT(a.flags, a.done, ep, wg);           // c_t visible device-wide

    // ======== phase 2: o-gate peephole = c_t @ W_oc ========
    f32x4 a20 = {}, a21 = {};
#pragma unroll
    for (int ks = 0; ks < 4; ++ks) {
      const int j8 = wave * 16 + ks * 4 + kgroup;
      cf0[ks] = ldfrag(C64, j8, mrow);        // save as carry for phase1(t+1)
      cf1[ks] = ldfrag(C64, j8, mrow + 16);
      a20 = mfma16(cf0[ks], bch[ks], a20);
      a20 = mfma16(cf0[ks], bcl[ks], a20);
      a21 = mfma16(cf1[ks], bch[ks], a21);
      a21 = mfma16(cf1[ks], bcl[ks], a21);
    }
#pragma unroll
    for (int v = 0; v < 4; ++v) {
      scr[((wave * 2 + 0) * 16 + rq + v) * 17 + col] = a20[v];
      scr[((wave * 2 + 1) * 16 + rq + v) * 17 + col] = a21[v];
    }
    __syncthreads();
    if (tid < 128) {
      float s = o_pre;
#pragma unroll
      for (int w = 0; w < 8; ++w)
        s += scr[((w * 2 + (eb >> 4)) * 16 + (eb & 15)) * 17 + ejj * 4 + 3];
      float ov = 1.f / (1.f + expf(-s));
      float hv = ov * tanhf(c_reg);
      u32 hb = (u32)f2bf(hv);
      u32 hpart = __shfl_xor(hb, 1);
      if ((tid & 1) == 0) st32(a.hB + swidx, hb | (hpart << 16));
      if (t == 511) a.out[eb * 1024 + ej] = hv;
    }
    arriveT(a.flags, ++ep, wg);               // h_t barrier: arrive
    // ---- h-window: peephole MFMA chain for step t+1 (uses carried cf) ----
    {
      f32x4 npc0 = {}, npc1 = {};
#pragma unroll
      for (int ks = 0; ks < 4; ++ks) {
        npc0 = mfma16(cf0[ks], bch[ks], npc0);
        npc0 = mfma16(cf0[ks], bcl[ks], npc0);
        npc1 = mfma16(cf1[ks], bch[ks], npc1);
        npc1 = mfma16(cf1[ks], bcl[ks], npc1);
      }
      pc0 = npc0; pc1 = npc1;
    }
    waitT(a.flags, a.done, ep, wg);           // h_t visible device-wide
  }
}

extern "C" void kernel_launch(void* const* d_in, const int* in_sizes, int n_in,
                              void* d_out, int out_size, void* d_ws, size_t ws_size,
                              hipStream_t stream) {
  (void)in_sizes; (void)n_in; (void)out_size;
  RecArgs ra;
  ra.x    = (const float*)d_in[0];
  ra.W_ix = (const float*)d_in[1];
  ra.W_ih = (const float*)d_in[2];
  ra.W_ic = (const float*)d_in[3];
  ra.W_fx = (const float*)d_in[4];
  ra.W_fh = (const float*)d_in[5];
  ra.W_fc = (const float*)d_in[6];
  ra.W_cx = (const float*)d_in[7];
  ra.W_ch = (const float*)d_in[8];
  ra.W_ox = (const float*)d_in[9];
  ra.W_oh = (const float*)d_in[10];
  ra.W_oc = (const float*)d_in[11];
  ra.b_i  = (const float*)d_in[12];
  ra.b_f  = (const float*)d_in[13];
  ra.b_c  = (const float*)d_in[14];
  ra.b_o  = (const float*)d_in[15];

  char* ws = (char*)d_ws;
  size_t off = 0;
  auto alloc = [&](size_t bytes) {
    char* p = ws + off;
    off = (off + bytes + 255) & ~(size_t)255;
    return p;
  };
  ra.hB    = (u32*)alloc(32 * 1024 * 2);   // bf16 h plane, k-contiguous layout
  ra.cB    = (u32*)alloc(32 * 1024 * 2);   // bf16 c plane
  ra.flags = (u32*)alloc(1024);            // 256 per-block epoch flags
  ra.done  = (u32*)alloc(256);             // root broadcast epoch (own line)
  ra.out   = (float*)d_out;
  if (off > ws_size) return;               // visible failure if ws too small

  (void)hipMemsetAsync(ra.flags, 0, 1024, stream);
  (void)hipMemsetAsync(ra.done, 0, 256, stream);

  void* args[] = {&ra};
  hipError_t e = hipLaunchCooperativeKernel((void*)lstm_rec, dim3(256), dim3(512),
                                            args, 0, stream);
  if (e != hipSuccess) {
    // co-residency still holds: 1 block/CU x 256 blocks on 256 CUs
    lstm_rec<<<dim3(256), dim3(512), 0, stream>>>(ra);
  }
}

// Round 15
// 5226.760 us; speedup vs baseline: 2.8704x; 1.0442x over previous
//
#include <hip/hip_runtime.h>
#include <hip/hip_bf16.h>
#include <stdint.h>

typedef unsigned short u16;
typedef uint32_t u32;
typedef unsigned long long u64;
typedef float f32x4 __attribute__((ext_vector_type(4)));
typedef __bf16 bf16x8 __attribute__((ext_vector_type(8)));

__device__ inline u16 f2bf(float f) {
  __bf16 h = (__bf16)f;                 // RTNE
  return __builtin_bit_cast(u16, h);
}
__device__ inline f32x4 mfma16(bf16x8 a, bf16x8 b, f32x4 c) {
  return __builtin_amdgcn_mfma_f32_16x16x32_bf16(a, b, c, 0, 0, 0);
}
// split 8 contiguous fp32 into bf16 hi + lo fragments (cached loads)
__device__ inline void cvt8(const float* p, bf16x8& h, bf16x8& l) {
  f32x4 u = *(const f32x4*)p;
  f32x4 v = *(const f32x4*)(p + 4);
#pragma unroll
  for (int i = 0; i < 4; ++i) {
    float a = u[i]; __bf16 ah = (__bf16)a; h[i] = ah; l[i] = (__bf16)(a - (float)ah);
    float b = v[i]; __bf16 bh = (__bf16)b; h[i + 4] = bh; l[i + 4] = (__bf16)(b - (float)bh);
  }
}
// gather 8 k-strided fp32 (stride 1024 floats) into bf16 hi + lo fragments
__device__ inline void gather8(const float* p, bf16x8& h, bf16x8& l) {
#pragma unroll
  for (int e = 0; e < 8; ++e) {
    float f = p[(size_t)e * 1024];
    __bf16 x = (__bf16)f;
    h[e] = x; l[e] = (__bf16)(f - (float)x);
  }
}

// ---- coherence-point (bypass) accessors ----
__device__ inline u64 ld64(const u64* p) {
  return __hip_atomic_load(p, __ATOMIC_RELAXED, __HIP_MEMORY_SCOPE_AGENT);
}
__device__ inline u32 ld32(const u32* p) {
  return __hip_atomic_load(p, __ATOMIC_RELAXED, __HIP_MEMORY_SCOPE_AGENT);
}
__device__ inline void st32(u32* p, u32 v) {
  __hip_atomic_store(p, v, __ATOMIC_RELAXED, __HIP_MEMORY_SCOPE_AGENT);
}

// bf16 state plane [32 b][1024 j], 64KB, k-contiguous layout (u16 units):
//   idx16(b,j) = (j>>3)<<8 | ((j>>2)&1)<<7 | (b&31)<<2 | (j&3)
// A wave fragment (8 k-elems, one row) = 2 coalesced ld64.  [R8-exact]
struct B16Pair { u64 a, b; };
__device__ inline bf16x8 ldfrag(const u64* base, int j8, int row) {
  B16Pair p;
  p.a = ld64(base + (j8 << 6) + row);
  p.b = ld64(base + (j8 << 6) + 32 + row);
  return __builtin_bit_cast(bf16x8, p);
}

struct RecArgs {
  const float* x;
  const float *W_ix, *W_ih, *W_ic, *W_fx, *W_fh, *W_fc, *W_cx, *W_ch;
  const float *W_ox, *W_oh, *W_oc;
  const float *b_i, *b_f, *b_c, *b_o;
  u32 *hB, *cB;          // bf16 state planes, 64KB each
  u32* flags;            // 256 per-block epoch flags
  u32* done;             // 16 replicated release lines (64B apart)
  float* out;
};

// R8 tree barrier with CONTENTION-FREE release: root publishes the epoch to
// 16 replicated lines; each leaf polls only line (wg&15) -> <=16 pollers per
// IF$ line instead of 256 (per-line request rate was the latency killer in
// R5/R11/R12 — same fix applied to the release side).
__device__ inline void arriveT(u32* flags, unsigned ep, int wg) {
  __syncthreads();                      // drain state stores to IF$ first
  if (threadIdx.x == 0) st32(flags + wg, ep);
}
__device__ inline void waitT(u32* flags, u32* done, unsigned ep, int wg) {
  const int tid = threadIdx.x;
  if (wg == 0) {
    const int wv = tid >> 6, ln = tid & 63;
    if (wv < 4) {
      int it = 0;
      for (;;) {
        u32 v = ld32(flags + wv * 64 + ln);
        if (__ballot(v >= ep) == ~0ull) break;
        if (++it > 400000) break;
        __builtin_amdgcn_s_sleep(1);
      }
    }
    __syncthreads();                    // all quarter-groups confirmed
    if (tid < 16) st32(done + tid * 16, ep);   // 16 parallel replica stores
  } else if (tid == 0) {
    const u32* dp = done + (wg & 15) * 16;
    int it = 0;
    while (ld32(dp) < ep && it < 400000) {
      __builtin_amdgcn_s_sleep(1);
      ++it;
    }
  }
  __syncthreads();
}

// Persistent LSTM: 256 blocks x 512 threads (8 waves). Block owns 4 H-cols
// of each gate; wave w owns K-slice. Weights register-resident (hi/lo bf16).
// R14 structure (window-filled tree barrier), release lines replicated x16.
// Numerics bit-exact vs R8/R14 (absmax 0.01708984).
__global__ __launch_bounds__(512, 1) void lstm_rec(RecArgs a) {
  __shared__ float scr[8 * 2 * 16 * 17];     // [wave][mt][row][col], padded

  const int tid = threadIdx.x;
  const int wg = blockIdx.x;
  const int j0 = wg * 4;
  const int lane = tid & 63;
  const int wave = tid >> 6;
  const int mrow = lane & 15;               // A-row (batch) lane index
  const int kgroup = lane >> 4;             // k sub-block 0..3
  const int kq = kgroup * 8;
  const int kw = wave * 128;                // per-wave K slice
  const int col = lane & 15;                // B/D column lane index
  const int rq = (lane >> 4) * 4;           // D row quad base

  const u64* H64 = (const u64*)a.hB;
  const u64* C64 = (const u64*)a.cB;

  // ---- one-time: B-fragments (weights) -> registers, hi/lo split ----
  const int fjj = col >> 2, fg = col & 3;   // col = jj*4 + g
  const int fj = j0 + fjj;
  const float* Wx = (fg == 0) ? a.W_ix : (fg == 1) ? a.W_fx : (fg == 2) ? a.W_cx : a.W_ox;
  const float* Wh = (fg == 0) ? a.W_ih : (fg == 1) ? a.W_fh : (fg == 2) ? a.W_ch : a.W_oh;
  const float* Wc = (fg == 0) ? a.W_ic : (fg == 1) ? a.W_fc : (fg == 3) ? a.W_oc : a.W_ic;

  bf16x8 bxh[4], bxl[4], bhh[4], bhl[4], bch[4], bcl[4];
#pragma unroll
  for (int ks = 0; ks < 4; ++ks) {
    const size_t k8 = (size_t)(kw + ks * 32 + kq);
    gather8(Wx + k8 * 1024 + fj, bxh[ks], bxl[ks]);
    gather8(Wh + k8 * 1024 + fj, bhh[ks], bhl[ks]);
    if (fg != 2) {
      gather8(Wc + k8 * 1024 + fj, bch[ks], bcl[ks]);
    } else {
      bf16x8 z = {};
      bch[ks] = z; bcl[ks] = z;
    }
  }

  // elementwise thread constants (threads 0..127: b = tid>>2, jj = tid&3)
  const int eb = tid >> 2, ejj = tid & 3, ej = j0 + (tid & 3);
  const u32 swidx = ((u32)(ej >> 3) << 7) | ((u32)((ej >> 2) & 1) << 6)
                  | ((u32)eb << 1) | ((u32)(ej >> 1) & 1);
  // ---- zero own slice of state (bypass stores, even threads store pairs) --
  if (tid < 128 && (tid & 1) == 0) {
    st32(a.hB + swidx, 0u);
    st32(a.cB + swidx, 0u);
  }
  float bi = 0.f, bfv = 0.f, bcv = 0.f, bo = 0.f;
  if (tid < 128) {
    bi = a.b_i[ej]; bfv = a.b_f[eb * 1024 + ej]; bcv = a.b_c[ej]; bo = a.b_o[ej];
  }

  unsigned ep = 0;
  arriveT(a.flags, ++ep, wg);
  // init-barrier window: prefetch x(0) fragments
  bf16x8 xph0[4], xpl0[4], xph1[4], xpl1[4];
#pragma unroll
  for (int ks = 0; ks < 4; ++ks) {
    const float* xp = a.x + ((size_t)mrow << 10) + kw + ks * 32 + kq;
    cvt8(xp, xph0[ks], xpl0[ks]);
    cvt8(xp + (16 << 10), xph1[ks], xpl1[ks]);
  }
  waitT(a.flags, a.done, ep, wg);

  float c_reg = 0.f, o_pre = 0.f;
  bf16x8 cf0[4] = {}, cf1[4] = {};          // carried c_{t-1} fragments
  // prologue peephole chain for t=0 (zero cf -> exact 0, as in R8's t=0)
  f32x4 pc0 = {}, pc1 = {};
#pragma unroll
  for (int ks = 0; ks < 4; ++ks) {
    pc0 = mfma16(cf0[ks], bch[ks], pc0);
    pc0 = mfma16(cf0[ks], bcl[ks], pc0);
    pc1 = mfma16(cf1[ks], bch[ks], pc1);
    pc1 = mfma16(cf1[ks], bcl[ks], pc1);
  }

  for (int t = 0; t < 512; ++t) {
    // ======== phase 1: pre-gates = x@Wx + h@Wh (+ pc from window) ========
    f32x4 acc0 = {}, acc1 = {};
#pragma unroll
    for (int ks = 0; ks < 4; ++ks) {
      const int j8 = wave * 16 + ks * 4 + kgroup;
      bf16x8 ah0 = ldfrag(H64, j8, mrow);
      bf16x8 ah1 = ldfrag(H64, j8, mrow + 16);
      acc0 = mfma16(xph0[ks], bxh[ks], acc0);
      acc0 = mfma16(xpl0[ks], bxh[ks], acc0);
      acc0 = mfma16(xph0[ks], bxl[ks], acc0);
      acc0 = mfma16(ah0, bhh[ks], acc0);
      acc0 = mfma16(ah0, bhl[ks], acc0);
      acc1 = mfma16(xph1[ks], bxh[ks], acc1);
      acc1 = mfma16(xpl1[ks], bxh[ks], acc1);
      acc1 = mfma16(xph1[ks], bxl[ks], acc1);
      acc1 = mfma16(ah1, bhh[ks], acc1);
      acc1 = mfma16(ah1, bhl[ks], acc1);
    }
    {
      const bool take_pc = (col & 3) != 3;   // o-gate peephole deferred
#pragma unroll
      for (int v = 0; v < 4; ++v) {
        scr[((wave * 2 + 0) * 16 + rq + v) * 17 + col] = acc0[v] + (take_pc ? pc0[v] : 0.f);
        scr[((wave * 2 + 1) * 16 + rq + v) * 17 + col] = acc1[v] + (take_pc ? pc1[v] : 0.f);
      }
    }
    __syncthreads();
    if (tid < 128) {
      float pre[4];
#pragma unroll
      for (int g = 0; g < 4; ++g) {
        float s = 0.f;
#pragma unroll
        for (int w = 0; w < 8; ++w)
          s += scr[((w * 2 + (eb >> 4)) * 16 + (eb & 15)) * 17 + ejj * 4 + g];
        pre[g] = s;
      }
      float iv = 1.f / (1.f + expf(-(pre[0] + bi)));
      float fv = 1.f / (1.f + expf(-(pre[1] + bfv)));
      float cv = tanhf(pre[2] + bcv);
      c_reg = fv * c_reg + iv * cv;           // fp32 carry, owner thread
      u32 cb = (u32)f2bf(c_reg);
      u32 cpart = __shfl_xor(cb, 1);
      if ((tid & 1) == 0) st32(a.cB + swidx, cb | (cpart << 16));
      o_pre = pre[3] + bo;
    }
    arriveT(a.flags, ++ep, wg);               // c_t barrier: arrive
    // ---- c-window: prefetch + convert x(t+1) (L2-cached, independent) ----
    {
      const int tn = (t < 511) ? t + 1 : 511;
#pragma unroll
      for (int ks = 0; ks < 4; ++ks) {
        const float* xp = a.x + ((size_t)(tn * 32 + mrow) << 10) + kw + ks * 32 + kq;
        cvt8(xp, xph0[ks], xpl0[ks]);
        cvt8(xp + (16 << 10), xph1[ks], xpl1[ks]);
      }
    }
    waitT(a.flags, a.done, ep, wg);           // c_t visible device-wide

    // ======== phase 2: o-gate peephole = c_t @ W_oc ========
    f32x4 a20 = {}, a21 = {};
#pragma unroll
    for (int ks = 0; ks < 4; ++ks) {
      const int j8 = wave * 16 + ks * 4 + kgroup;
      cf0[ks] = ldfrag(C64, j8, mrow);        // save as carry for phase1(t+1)
      cf1[ks] = ldfrag(C64, j8, mrow + 16);
      a20 = mfma16(cf0[ks], bch[ks], a20);
      a20 = mfma16(cf0[ks], bcl[ks], a20);
      a21 = mfma16(cf1[ks], bch[ks], a21);
      a21 = mfma16(cf1[ks], bcl[ks], a21);
    }
#pragma unroll
    for (int v = 0; v < 4; ++v) {
      scr[((wave * 2 + 0) * 16 + rq + v) * 17 + col] = a20[v];
      scr[((wave * 2 + 1) * 16 + rq + v) * 17 + col] = a21[v];
    }
    __syncthreads();
    if (tid < 128) {
      float s = o_pre;
#pragma unroll
      for (int w = 0; w < 8; ++w)
        s += scr[((w * 2 + (eb >> 4)) * 16 + (eb & 15)) * 17 + ejj * 4 + 3];
      float ov = 1.f / (1.f + expf(-s));
      float hv = ov * tanhf(c_reg);
      u32 hb = (u32)f2bf(hv);
      u32 hpart = __shfl_xor(hb, 1);
      if ((tid & 1) == 0) st32(a.hB + swidx, hb | (hpart << 16));
      if (t == 511) a.out[eb * 1024 + ej] = hv;
    }
    arriveT(a.flags, ++ep, wg);               // h_t barrier: arrive
    // ---- h-window: peephole MFMA chain for step t+1 (uses carried cf) ----
    {
      f32x4 npc0 = {}, npc1 = {};
#pragma unroll
      for (int ks = 0; ks < 4; ++ks) {
        npc0 = mfma16(cf0[ks], bch[ks], npc0);
        npc0 = mfma16(cf0[ks], bcl[ks], npc0);
        npc1 = mfma16(cf1[ks], bch[ks], npc1);
        npc1 = mfma16(cf1[ks], bcl[ks], npc1);
      }
      pc0 = npc0; pc1 = npc1;
    }
    waitT(a.flags, a.done, ep, wg);           // h_t visible device-wide
  }
}

extern "C" void kernel_launch(void* const* d_in, const int* in_sizes, int n_in,
                              void* d_out, int out_size, void* d_ws, size_t ws_size,
                              hipStream_t stream) {
  (void)in_sizes; (void)n_in; (void)out_size;
  RecArgs ra;
  ra.x    = (const float*)d_in[0];
  ra.W_ix = (const float*)d_in[1];
  ra.W_ih = (const float*)d_in[2];
  ra.W_ic = (const float*)d_in[3];
  ra.W_fx = (const float*)d_in[4];
  ra.W_fh = (const float*)d_in[5];
  ra.W_fc = (const float*)d_in[6];
  ra.W_cx = (const float*)d_in[7];
  ra.W_ch = (const float*)d_in[8];
  ra.W_ox = (const float*)d_in[9];
  ra.W_oh = (const float*)d_in[10];
  ra.W_oc = (const float*)d_in[11];
  ra.b_i  = (const float*)d_in[12];
  ra.b_f  = (const float*)d_in[13];
  ra.b_c  = (const float*)d_in[14];
  ra.b_o  = (const float*)d_in[15];

  char* ws = (char*)d_ws;
  size_t off = 0;
  auto alloc = [&](size_t bytes) {
    char* p = ws + off;
    off = (off + bytes + 255) & ~(size_t)255;
    return p;
  };
  ra.hB    = (u32*)alloc(32 * 1024 * 2);   // bf16 h plane, k-contiguous layout
  ra.cB    = (u32*)alloc(32 * 1024 * 2);   // bf16 c plane
  ra.flags = (u32*)alloc(1024);            // 256 per-block epoch flags
  ra.done  = (u32*)alloc(16 * 64);         // 16 replicated release lines
  ra.out   = (float*)d_out;
  if (off > ws_size) return;               // visible failure if ws too small

  (void)hipMemsetAsync(ra.flags, 0, 1024, stream);
  (void)hipMemsetAsync(ra.done, 0, 16 * 64, stream);

  void* args[] = {&ra};
  hipError_t e = hipLaunchCooperativeKernel((void*)lstm_rec, dim3(256), dim3(512),
                                            args, 0, stream);
  if (e != hipSuccess) {
    // co-residency still holds: 1 block/CU x 256 blocks on 256 CUs
    lstm_rec<<<dim3(256), dim3(512), 0, stream>>>(ra);
  }
}

// Round 16
// 5056.100 us; speedup vs baseline: 2.9673x; 1.0338x over previous
//
#include <hip/hip_runtime.h>
#include <hip/hip_bf16.h>
#include <stdint.h>

typedef unsigned short u16;
typedef uint32_t u32;
typedef unsigned long long u64;
typedef float f32x4 __attribute__((ext_vector_type(4)));
typedef __bf16 bf16x8 __attribute__((ext_vector_type(8)));

__device__ inline u16 f2bf(float f) {
  __bf16 h = (__bf16)f;                 // RTNE
  return __builtin_bit_cast(u16, h);
}
__device__ inline f32x4 mfma16(bf16x8 a, bf16x8 b, f32x4 c) {
  return __builtin_amdgcn_mfma_f32_16x16x32_bf16(a, b, c, 0, 0, 0);
}
// split 8 contiguous fp32 into bf16 hi + lo fragments (cached loads)
__device__ inline void cvt8(const float* p, bf16x8& h, bf16x8& l) {
  f32x4 u = *(const f32x4*)p;
  f32x4 v = *(const f32x4*)(p + 4);
#pragma unroll
  for (int i = 0; i < 4; ++i) {
    float a = u[i]; __bf16 ah = (__bf16)a; h[i] = ah; l[i] = (__bf16)(a - (float)ah);
    float b = v[i]; __bf16 bh = (__bf16)b; h[i + 4] = bh; l[i + 4] = (__bf16)(b - (float)bh);
  }
}
// gather 8 k-strided fp32 (stride 1024 floats) into bf16 hi + lo fragments
__device__ inline void gather8(const float* p, bf16x8& h, bf16x8& l) {
#pragma unroll
  for (int e = 0; e < 8; ++e) {
    float f = p[(size_t)e * 1024];
    __bf16 x = (__bf16)f;
    h[e] = x; l[e] = (__bf16)(f - (float)x);
  }
}

// ---- coherence-point (bypass) accessors ----
__device__ inline u64 ld64(const u64* p) {
  return __hip_atomic_load(p, __ATOMIC_RELAXED, __HIP_MEMORY_SCOPE_AGENT);
}
__device__ inline void st32(u32* p, u32 v) {
  __hip_atomic_store(p, v, __ATOMIC_RELAXED, __HIP_MEMORY_SCOPE_AGENT);
}

// bf16 state plane [32 b][1024 j], 64KB, k-contiguous layout (u16 units):
//   idx16(b,j) = (j>>3)<<8 | ((j>>2)&1)<<7 | (b&31)<<2 | (j&3)
// A wave fragment (8 k-elems, one row) = 2 coalesced ld64.  [R8-exact]
struct B16Pair { u64 a, b; };
__device__ inline bf16x8 ldfrag(const u64* base, int j8, int row) {
  B16Pair p;
  p.a = ld64(base + (j8 << 6) + row);
  p.b = ld64(base + (j8 << 6) + 32 + row);
  return __builtin_bit_cast(bf16x8, p);
}

struct RecArgs {
  const float* x;
  const float *W_ix, *W_ih, *W_ic, *W_fx, *W_fh, *W_fc, *W_cx, *W_ch;
  const float *W_ox, *W_oh, *W_oc;
  const float *b_i, *b_f, *b_c, *b_o;
  u32 *hB, *cB;          // bf16 state planes, 64KB each
  u32* flags;            // 256 per-block epoch flags
  float* out;
};

// All-to-all barrier (no root hop): arrive = own flag store; wait = wave 0
// polls all 256 flags (2x ld64/lane, 16 lines total -> ~0.4G req/line,
// the proven-clean rate). Removes root-detect + done-publish hops.
__device__ inline void arriveT(u32* flags, unsigned ep, int wg) {
  __syncthreads();                      // drain state stores to IF$ first
  if (threadIdx.x == 0) st32(flags + wg, ep);
}
__device__ inline void waitA(const u32* flags, unsigned ep) {
  if (threadIdx.x < 64) {
    const u64* f = (const u64*)flags + threadIdx.x * 2;
    int it = 0;
    for (;;) {
      u64 q0 = ld64(f), q1 = ld64(f + 1);
      bool ok = ((u32)q0 >= ep) & ((u32)(q0 >> 32) >= ep) &
                ((u32)q1 >= ep) & ((u32)(q1 >> 32) >= ep);
      if (__ballot(ok) == ~0ull) break;
      if (++it > 400000) break;
      __builtin_amdgcn_s_sleep(1);
    }
  }
  __syncthreads();
}

// Persistent LSTM: 256 blocks x 512 threads (8 waves). Block owns 4 H-cols
// of each gate; wave w owns K-slice. Weights register-resident (hi/lo bf16).
// R15 structure with all-to-all barrier. Numerics bit-exact (0.01708984).
__global__ __launch_bounds__(512, 1) void lstm_rec(RecArgs a) {
  __shared__ float scr[8 * 2 * 16 * 17];     // [wave][mt][row][col], padded

  const int tid = threadIdx.x;
  const int wg = blockIdx.x;
  const int j0 = wg * 4;
  const int lane = tid & 63;
  const int wave = tid >> 6;
  const int mrow = lane & 15;               // A-row (batch) lane index
  const int kgroup = lane >> 4;             // k sub-block 0..3
  const int kq = kgroup * 8;
  const int kw = wave * 128;                // per-wave K slice
  const int col = lane & 15;                // B/D column lane index
  const int rq = (lane >> 4) * 4;           // D row quad base

  const u64* H64 = (const u64*)a.hB;
  const u64* C64 = (const u64*)a.cB;

  // ---- one-time: B-fragments (weights) -> registers, hi/lo split ----
  const int fjj = col >> 2, fg = col & 3;   // col = jj*4 + g
  const int fj = j0 + fjj;
  const float* Wx = (fg == 0) ? a.W_ix : (fg == 1) ? a.W_fx : (fg == 2) ? a.W_cx : a.W_ox;
  const float* Wh = (fg == 0) ? a.W_ih : (fg == 1) ? a.W_fh : (fg == 2) ? a.W_ch : a.W_oh;
  const float* Wc = (fg == 0) ? a.W_ic : (fg == 1) ? a.W_fc : (fg == 3) ? a.W_oc : a.W_ic;

  bf16x8 bxh[4], bxl[4], bhh[4], bhl[4], bch[4], bcl[4];
#pragma unroll
  for (int ks = 0; ks < 4; ++ks) {
    const size_t k8 = (size_t)(kw + ks * 32 + kq);
    gather8(Wx + k8 * 1024 + fj, bxh[ks], bxl[ks]);
    gather8(Wh + k8 * 1024 + fj, bhh[ks], bhl[ks]);
    if (fg != 2) {
      gather8(Wc + k8 * 1024 + fj, bch[ks], bcl[ks]);
    } else {
      bf16x8 z = {};
      bch[ks] = z; bcl[ks] = z;
    }
  }

  // elementwise thread constants (threads 0..127: b = tid>>2, jj = tid&3)
  const int eb = tid >> 2, ejj = tid & 3, ej = j0 + (tid & 3);
  const u32 swidx = ((u32)(ej >> 3) << 7) | ((u32)((ej >> 2) & 1) << 6)
                  | ((u32)eb << 1) | ((u32)(ej >> 1) & 1);
  // ---- zero own slice of state (bypass stores, even threads store pairs) --
  if (tid < 128 && (tid & 1) == 0) {
    st32(a.hB + swidx, 0u);
    st32(a.cB + swidx, 0u);
  }
  float bi = 0.f, bfv = 0.f, bcv = 0.f, bo = 0.f;
  if (tid < 128) {
    bi = a.b_i[ej]; bfv = a.b_f[eb * 1024 + ej]; bcv = a.b_c[ej]; bo = a.b_o[ej];
  }

  unsigned ep = 0;
  arriveT(a.flags, ++ep, wg);
  // init-barrier window: prefetch x(0) fragments
  bf16x8 xph0[4], xpl0[4], xph1[4], xpl1[4];
#pragma unroll
  for (int ks = 0; ks < 4; ++ks) {
    const float* xp = a.x + ((size_t)mrow << 10) + kw + ks * 32 + kq;
    cvt8(xp, xph0[ks], xpl0[ks]);
    cvt8(xp + (16 << 10), xph1[ks], xpl1[ks]);
  }
  waitA(a.flags, ep);

  float c_reg = 0.f, o_pre = 0.f;
  bf16x8 cf0[4] = {}, cf1[4] = {};          // carried c_{t-1} fragments
  // prologue peephole chain for t=0 (zero cf -> exact 0, as in R8's t=0)
  f32x4 pc0 = {}, pc1 = {};
#pragma unroll
  for (int ks = 0; ks < 4; ++ks) {
    pc0 = mfma16(cf0[ks], bch[ks], pc0);
    pc0 = mfma16(cf0[ks], bcl[ks], pc0);
    pc1 = mfma16(cf1[ks], bch[ks], pc1);
    pc1 = mfma16(cf1[ks], bcl[ks], pc1);
  }

  for (int t = 0; t < 512; ++t) {
    // ======== phase 1: pre-gates = x@Wx + h@Wh (+ pc from window) ========
    f32x4 acc0 = {}, acc1 = {};
#pragma unroll
    for (int ks = 0; ks < 4; ++ks) {
      const int j8 = wave * 16 + ks * 4 + kgroup;
      bf16x8 ah0 = ldfrag(H64, j8, mrow);
      bf16x8 ah1 = ldfrag(H64, j8, mrow + 16);
      acc0 = mfma16(xph0[ks], bxh[ks], acc0);
      acc0 = mfma16(xpl0[ks], bxh[ks], acc0);
      acc0 = mfma16(xph0[ks], bxl[ks], acc0);
      acc0 = mfma16(ah0, bhh[ks], acc0);
      acc0 = mfma16(ah0, bhl[ks], acc0);
      acc1 = mfma16(xph1[ks], bxh[ks], acc1);
      acc1 = mfma16(xpl1[ks], bxh[ks], acc1);
      acc1 = mfma16(xph1[ks], bxl[ks], acc1);
      acc1 = mfma16(ah1, bhh[ks], acc1);
      acc1 = mfma16(ah1, bhl[ks], acc1);
    }
    {
      const bool take_pc = (col & 3) != 3;   // o-gate peephole deferred
#pragma unroll
      for (int v = 0; v < 4; ++v) {
        scr[((wave * 2 + 0) * 16 + rq + v) * 17 + col] = acc0[v] + (take_pc ? pc0[v] : 0.f);
        scr[((wave * 2 + 1) * 16 + rq + v) * 17 + col] = acc1[v] + (take_pc ? pc1[v] : 0.f);
      }
    }
    __syncthreads();
    if (tid < 128) {
      float pre[4];
#pragma unroll
      for (int g = 0; g < 4; ++g) {
        float s = 0.f;
#pragma unroll
        for (int w = 0; w < 8; ++w)
          s += scr[((w * 2 + (eb >> 4)) * 16 + (eb & 15)) * 17 + ejj * 4 + g];
        pre[g] = s;
      }
      float iv = 1.f / (1.f + expf(-(pre[0] + bi)));
      float fv = 1.f / (1.f + expf(-(pre[1] + bfv)));
      float cv = tanhf(pre[2] + bcv);
      c_reg = fv * c_reg + iv * cv;           // fp32 carry, owner thread
      u32 cb = (u32)f2bf(c_reg);
      u32 cpart = __shfl_xor(cb, 1);
      if ((tid & 1) == 0) st32(a.cB + swidx, cb | (cpart << 16));
      o_pre = pre[3] + bo;
    }
    arriveT(a.flags, ++ep, wg);               // c_t barrier: arrive
    // ---- c-window: prefetch + convert x(t+1) (L2-cached, independent) ----
    {
      const int tn = (t < 511) ? t + 1 : 511;
#pragma unroll
      for (int ks = 0; ks < 4; ++ks) {
        const float* xp = a.x + ((size_t)(tn * 32 + mrow) << 10) + kw + ks * 32 + kq;
        cvt8(xp, xph0[ks], xpl0[ks]);
        cvt8(xp + (16 << 10), xph1[ks], xpl1[ks]);
      }
    }
    waitA(a.flags, ep);                       // c_t visible device-wide

    // ======== phase 2: o-gate peephole = c_t @ W_oc ========
    f32x4 a20 = {}, a21 = {};
#pragma unroll
    for (int ks = 0; ks < 4; ++ks) {
      const int j8 = wave * 16 + ks * 4 + kgroup;
      cf0[ks] = ldfrag(C64, j8, mrow);        // save as carry for phase1(t+1)
      cf1[ks] = ldfrag(C64, j8, mrow + 16);
      a20 = mfma16(cf0[ks], bch[ks], a20);
      a20 = mfma16(cf0[ks], bcl[ks], a20);
      a21 = mfma16(cf1[ks], bch[ks], a21);
      a21 = mfma16(cf1[ks], bcl[ks], a21);
    }
#pragma unroll
    for (int v = 0; v < 4; ++v) {
      scr[((wave * 2 + 0) * 16 + rq + v) * 17 + col] = a20[v];
      scr[((wave * 2 + 1) * 16 + rq + v) * 17 + col] = a21[v];
    }
    __syncthreads();
    if (tid < 128) {
      float s = o_pre;
#pragma unroll
      for (int w = 0; w < 8; ++w)
        s += scr[((w * 2 + (eb >> 4)) * 16 + (eb & 15)) * 17 + ejj * 4 + 3];
      float ov = 1.f / (1.f + expf(-s));
      float hv = ov * tanhf(c_reg);
      u32 hb = (u32)f2bf(hv);
      u32 hpart = __shfl_xor(hb, 1);
      if ((tid & 1) == 0) st32(a.hB + swidx, hb | (hpart << 16));
      if (t == 511) a.out[eb * 1024 + ej] = hv;
    }
    arriveT(a.flags, ++ep, wg);               // h_t barrier: arrive
    // ---- h-window: peephole MFMA chain for step t+1 (uses carried cf) ----
    {
      f32x4 npc0 = {}, npc1 = {};
#pragma unroll
      for (int ks = 0; ks < 4; ++ks) {
        npc0 = mfma16(cf0[ks], bch[ks], npc0);
        npc0 = mfma16(cf0[ks], bcl[ks], npc0);
        npc1 = mfma16(cf1[ks], bch[ks], npc1);
        npc1 = mfma16(cf1[ks], bcl[ks], npc1);
      }
      pc0 = npc0; pc1 = npc1;
    }
    waitA(a.flags, ep);                       // h_t visible device-wide
  }
}

extern "C" void kernel_launch(void* const* d_in, const int* in_sizes, int n_in,
                              void* d_out, int out_size, void* d_ws, size_t ws_size,
                              hipStream_t stream) {
  (void)in_sizes; (void)n_in; (void)out_size;
  RecArgs ra;
  ra.x    = (const float*)d_in[0];
  ra.W_ix = (const float*)d_in[1];
  ra.W_ih = (const float*)d_in[2];
  ra.W_ic = (const float*)d_in[3];
  ra.W_fx = (const float*)d_in[4];
  ra.W_fh = (const float*)d_in[5];
  ra.W_fc = (const float*)d_in[6];
  ra.W_cx = (const float*)d_in[7];
  ra.W_ch = (const float*)d_in[8];
  ra.W_ox = (const float*)d_in[9];
  ra.W_oh = (const float*)d_in[10];
  ra.W_oc = (const float*)d_in[11];
  ra.b_i  = (const float*)d_in[12];
  ra.b_f  = (const float*)d_in[13];
  ra.b_c  = (const float*)d_in[14];
  ra.b_o  = (const float*)d_in[15];

  char* ws = (char*)d_ws;
  size_t off = 0;
  auto alloc = [&](size_t bytes) {
    char* p = ws + off;
    off = (off + bytes + 255) & ~(size_t)255;
    return p;
  };
  ra.hB    = (u32*)alloc(32 * 1024 * 2);   // bf16 h plane, k-contiguous layout
  ra.cB    = (u32*)alloc(32 * 1024 * 2);   // bf16 c plane
  ra.flags = (u32*)alloc(1024);            // 256 per-block epoch flags
  ra.out   = (float*)d_out;
  if (off > ws_size) return;               // visible failure if ws too small

  (void)hipMemsetAsync(ra.flags, 0, 1024, stream);

  void* args[] = {&ra};
  hipError_t e = hipLaunchCooperativeKernel((void*)lstm_rec, dim3(256), dim3(512),
                                            args, 0, stream);
  if (e != hipSuccess) {
    // co-residency still holds: 1 block/CU x 256 blocks on 256 CUs
    lstm_rec<<<dim3(256), dim3(512), 0, stream>>>(ra);
  }
}